// Round 1
// baseline (22341.779 us; speedup 1.0000x reference)
//
#include <hip/hip_runtime.h>
#include <hip/hip_cooperative_groups.h>

namespace cg = cooperative_groups;

#define B_ 16
#define T_ 512
#define P_ 2048
#define SN_ 256
#define SD_ 1024
#define NB_DEN 64
#define NB_NUM 16
#define NBLK (NB_DEN + NB_NUM)
#define NTHR 256

// Forward recursion in exp-space:
//   q_{t+1}[b,s'] = (sum_s q_t[b,s] * W[s,s']) / M_t[b] * exp(e_t[b,s'])
//   logscale[b]  += log M_t[b]            (only while t < seqlen[b])
// W = exp(trans) <= 1, M = per-row max of q (triple-buffered: read t%3,
// atomicMax into (t+1)%3, zero (t+2)%3 — last read at t-1, so safe).
template<int S>
__device__ __forceinline__ void run_path(
    cg::grid_group& grid,
    const float* __restrict__ input, const int* __restrict__ seqlen,
    const int* __restrict__ pdf, const float* __restrict__ Wm,
    float* __restrict__ Q, float* __restrict__ M, float* __restrict__ L,
    int colbase, bool lead)
{
  const int tid = threadIdx.x;
  const int b   = tid >> 4;              // 16 batch rows
  const int c   = colbase + (tid & 15);  // 16 columns per block
  const int slen = seqlen[b];
  const size_t inbase = (size_t)b * T_ * P_;
  const int mycol_pdf = pdf[c];

  int slb = 0;
  if (lead && tid < B_) slb = seqlen[tid];

  for (int t = 1; t < T_; ++t) {
    const int pr = t & 1;
    const int pw = pr ^ 1;
    const int mr = t % 3, mw = (t + 1) % 3, mz = (t + 2) % 3;
    const float* __restrict__ qr = Q + pr * B_ * S + b * S;

    float acc = 0.f;
    const float* wrow = Wm + c;
    #pragma unroll 4
    for (int s = 0; s < S; s += 4) {
      float4 qv = *(const float4*)(qr + s);
      acc = fmaf(qv.x, wrow[0],     acc);
      acc = fmaf(qv.y, wrow[S],     acc);
      acc = fmaf(qv.z, wrow[2 * S], acc);
      acc = fmaf(qv.w, wrow[3 * S], acc);
      wrow += 4 * S;
    }

    const float Mv = M[mr * B_ + b];
    float val;
    if (t < slen) {
      const float e = input[inbase + (size_t)t * P_ + mycol_pdf];
      val = (acc / Mv) * __expf(e);
    } else {
      val = qr[c];  // frozen sequence: carry q through unchanged
    }
    Q[pw * B_ * S + b * S + c] = val;

    // per-(b, slab) max over the 16 lanes sharing b -> device atomicMax
    float mx = val;
    mx = fmaxf(mx, __shfl_xor(mx, 1));
    mx = fmaxf(mx, __shfl_xor(mx, 2));
    mx = fmaxf(mx, __shfl_xor(mx, 4));
    mx = fmaxf(mx, __shfl_xor(mx, 8));
    if ((tid & 15) == 0)
      atomicMax((unsigned int*)(M + mw * B_ + b), __float_as_uint(mx)); // q >= 0: uint order == float order

    if (lead && tid < B_) {
      if (t < slb) L[tid] += __logf(M[mr * B_ + tid]);
      M[mz * B_ + tid] = 0.0f;   // untouched by anyone at step t; last read at t-1
    }
    __threadfence();
    grid.sync();
  }
}

__global__ __launch_bounds__(NTHR) void lfmmi_kernel(
    const float* __restrict__ input, const int* __restrict__ seqlen,
    const float* __restrict__ num_init, const float* __restrict__ num_trans,
    const float* __restrict__ num_final, const int* __restrict__ num_pdf,
    const float* __restrict__ den_init, const float* __restrict__ den_trans,
    const float* __restrict__ den_final, const int* __restrict__ den_pdf,
    float* __restrict__ out, float* __restrict__ ws)
{
  cg::grid_group grid = cg::this_grid();
  float* WD = ws;                       // [SD][SD] exp(den_trans)
  float* WN = WD + SD_ * SD_;           // [SN][SN]
  float* QD = WN + SN_ * SN_;           // [2][B][SD]
  float* QN = QD + 2 * B_ * SD_;        // [2][B][SN]
  float* MD = QN + 2 * B_ * SN_;        // [3][B]
  float* MN = MD + 3 * B_;              // [3][B]
  float* LD = MN + 3 * B_;              // [B] den logscale
  float* LN = LD + B_;                  // [B] num logscale

  const int tid = threadIdx.x;
  const int bid = blockIdx.x;
  const int gtid = bid * NTHR + tid;
  const int gsz  = NBLK * NTHR;
  __shared__ float sred[NTHR];

  // Phase 0: W = exp(trans) (ws is re-poisoned every launch -> recompute)
  {
    const float4* src = (const float4*)den_trans;
    float4* dst = (float4*)WD;
    for (int i = gtid; i < (SD_ * SD_) / 4; i += gsz) {
      float4 v = src[i];
      v.x = __expf(v.x); v.y = __expf(v.y); v.z = __expf(v.z); v.w = __expf(v.w);
      dst[i] = v;
    }
    const float4* srn = (const float4*)num_trans;
    float4* dsn = (float4*)WN;
    for (int i = gtid; i < (SN_ * SN_) / 4; i += gsz) {
      float4 v = srn[i];
      v.x = __expf(v.x); v.y = __expf(v.y); v.z = __expf(v.z); v.w = __expf(v.w);
      dsn[i] = v;
    }
  }

  // Phase 0b: alpha0 = init + emis[:,0,:], normalized into q0 (buffer 1)
  if (bid < B_) {
    const int b = bid;
    float a0[4]; float lmax = -3.4e38f;
    for (int k = 0; k < 4; ++k) {
      const int s = tid + k * NTHR;
      const float a = den_init[s] + input[(size_t)b * T_ * P_ + den_pdf[s]];
      a0[k] = a; lmax = fmaxf(lmax, a);
    }
    sred[tid] = lmax; __syncthreads();
    for (int off = 128; off; off >>= 1) { if (tid < off) sred[tid] = fmaxf(sred[tid], sred[tid + off]); __syncthreads(); }
    const float m = sred[0];
    for (int k = 0; k < 4; ++k) {
      const int s = tid + k * NTHR;
      QD[1 * B_ * SD_ + b * SD_ + s] = __expf(a0[k] - m);
    }
    if (tid == 0) { LD[b] = m; MD[1 * B_ + b] = 1.0f; MD[0 * B_ + b] = 0.0f; MD[2 * B_ + b] = 0.0f; }
  } else if (bid < 2 * B_) {
    const int b = bid - B_;
    const float a = num_init[tid] + input[(size_t)b * T_ * P_ + num_pdf[tid]];
    sred[tid] = a; __syncthreads();
    for (int off = 128; off; off >>= 1) { if (tid < off) sred[tid] = fmaxf(sred[tid], sred[tid + off]); __syncthreads(); }
    const float m = sred[0];
    QN[1 * B_ * SN_ + b * SN_ + tid] = __expf(a - m);
    if (tid == 0) { LN[b] = m; MN[1 * B_ + b] = 1.0f; MN[0 * B_ + b] = 0.0f; MN[2 * B_ + b] = 0.0f; }
  }
  __threadfence();
  grid.sync();

  // Main recursion: 511 steps, one grid.sync each
  if (bid < NB_DEN) {
    run_path<SD_>(grid, input, seqlen, den_pdf, WD, QD, MD, LD, bid * 16, bid == 0);
  } else {
    run_path<SN_>(grid, input, seqlen, num_pdf, WN, QN, MN, LN, (bid - NB_DEN) * 16, bid == NB_DEN);
  }

  // Final: logprob[b] = logscale[b] + log(sum_s q_T[b,s] * exp(final[s]))
  // q_T lives in buffer (T)&1 == 0. Only block 0 works here (after last sync).
  if (bid == 0) {
    float sden = 0.f, snum = 0.f;
    for (int b2 = 0; b2 < B_; ++b2) {
      float p = 0.f;
      for (int s = tid; s < SD_; s += NTHR) p += QD[b2 * SD_ + s] * __expf(den_final[s]);
      sred[tid] = p; __syncthreads();
      for (int off = 128; off; off >>= 1) { if (tid < off) sred[tid] += sred[tid + off]; __syncthreads(); }
      if (tid == 0) sden += LD[b2] + __logf(sred[0]);
      __syncthreads();
      float pn = QN[b2 * SN_ + tid] * __expf(num_final[tid]);
      sred[tid] = pn; __syncthreads();
      for (int off = 128; off; off >>= 1) { if (tid < off) sred[tid] += sred[tid + off]; __syncthreads(); }
      if (tid == 0) snum += LN[b2] + __logf(sred[0]);
      __syncthreads();
    }
    if (tid == 0) out[0] = -(snum - sden);
  }
}

extern "C" void kernel_launch(void* const* d_in, const int* in_sizes, int n_in,
                              void* d_out, int out_size, void* d_ws, size_t ws_size,
                              hipStream_t stream) {
  const float* input     = (const float*)d_in[0];
  const int*   seqlen    = (const int*)  d_in[1];
  const float* num_init  = (const float*)d_in[2];
  const float* num_trans = (const float*)d_in[3];
  const float* num_final = (const float*)d_in[4];
  const int*   num_pdf   = (const int*)  d_in[5];
  const float* den_init  = (const float*)d_in[6];
  const float* den_trans = (const float*)d_in[7];
  const float* den_final = (const float*)d_in[8];
  const int*   den_pdf   = (const int*)  d_in[9];
  float* out = (float*)d_out;
  float* ws  = (float*)d_ws;   // needs ~4.7 MB: W matrices + q double-buffers + M/logscale

  void* args[] = { &input, &seqlen, &num_init, &num_trans, &num_final, &num_pdf,
                   &den_init, &den_trans, &den_final, &den_pdf, &out, &ws };
  hipLaunchCooperativeKernel((void*)lfmmi_kernel, dim3(NBLK), dim3(NTHR),
                             args, 0, stream);
}

// Round 2
// 19298.848 us; speedup vs baseline: 1.1577x; 1.1577x over previous
//
#include <hip/hip_runtime.h>
#include <hip/hip_cooperative_groups.h>

namespace cg = cooperative_groups;

#define B_ 16
#define T_ 512
#define P_ 2048
#define SN_ 256
#define SD_ 1024
#define CPB 8                 // columns per block
#define NBD (SD_ / CPB)       // 128 den blocks
#define NBN (SN_ / CPB)       // 32 num blocks
#define NBLK (NBD + NBN)      // 160
#define NTHR 256              // 8 c x 2 k x 16 b

// Exp-space forward recursion, step t computes alpha_t:
//   q_t[b,c] = (sum_s q_{t-1}[b,s] * W[s,c]) / M[b] * exp(e_t[b,c])   (if t < seqlen[b])
// W slab (8 cols, transposed, padded) lives in LDS. q streamed from global
// (16-lane broadcast coalesced). M = lead block's own-8-column max (any
// reasonable scale works; exactness not required), single writer, 2 slots.
template<int S>
__device__ __forceinline__ void run_path(
    cg::grid_group& grid,
    const float* __restrict__ input, const int* __restrict__ seqlen,
    const int* __restrict__ pdf, const float* __restrict__ WL,
    float* __restrict__ red,
    float* __restrict__ Q, float* __restrict__ M, float* __restrict__ L,
    int colbase, bool lead)
{
  constexpr int SW = S + 4;     // padded LDS row stride (floats)
  constexpr int KH = S / 2;     // K half per thread
  const int tid = threadIdx.x;
  const int c = tid & 7;
  const int k = (tid >> 3) & 1;
  const int b = tid >> 4;
  const int cglob = colbase + c;
  const int slen = seqlen[b];
  const size_t inbase = (size_t)b * T_ * P_;
  const int mycol_pdf = pdf[cglob];
  const int slb = (lead && tid < B_) ? seqlen[tid] : 0;

  for (int t = 1; t < T_; ++t) {
    const int pr = t & 1, pw = pr ^ 1;
    const int mr = t & 1, mw = mr ^ 1;
    const float* __restrict__ Qr = Q + pr * B_ * S;
    float*       __restrict__ Qw = Q + pw * B_ * S;

    const bool live = (t < slen);
    float e_t = 0.f, carry = 0.f;
    if (k == 0) {
      if (live) e_t = input[inbase + (size_t)t * P_ + mycol_pdf];  // prefetch gather
      else      carry = Qr[b * S + cglob];                          // frozen sequence
    }

    const float* __restrict__ qrow = Qr + b * S + k * KH;   // global, L2-hot
    const float* __restrict__ wrow = WL + c * SW + k * KH;  // LDS
    float a0 = 0.f, a1 = 0.f, a2 = 0.f, a3 = 0.f;
    #pragma unroll 8
    for (int s = 0; s < KH; s += 4) {
      float4 qv = *(const float4*)(qrow + s);
      float4 wv = *(const float4*)(wrow + s);
      a0 = fmaf(qv.x, wv.x, a0);
      a1 = fmaf(qv.y, wv.y, a1);
      a2 = fmaf(qv.z, wv.z, a2);
      a3 = fmaf(qv.w, wv.w, a3);
    }
    red[tid] = (a0 + a1) + (a2 + a3);
    __syncthreads();

    if (k == 0) {
      const float acc = red[tid] + red[tid + 8];   // combine K halves
      const float Mv = M[mr * B_ + b];
      const float val = live ? (acc / Mv) * __expf(e_t) : carry;
      Qw[b * S + cglob] = val;
      if (lead) {
        float mx = val;
        mx = fmaxf(mx, __shfl_xor(mx, 1));
        mx = fmaxf(mx, __shfl_xor(mx, 2));
        mx = fmaxf(mx, __shfl_xor(mx, 4));
        if (c == 0) M[mw * B_ + b] = mx;   // plain store, single writer
      }
    }
    if (lead && tid < B_ && t < slb) L[tid] += __logf(M[mr * B_ + tid]);
    __threadfence();
    grid.sync();
  }
}

__global__ __launch_bounds__(NTHR) void lfmmi_kernel(
    const float* __restrict__ input, const int* __restrict__ seqlen,
    const float* __restrict__ num_init, const float* __restrict__ num_trans,
    const float* __restrict__ num_final, const int* __restrict__ num_pdf,
    const float* __restrict__ den_init, const float* __restrict__ den_trans,
    const float* __restrict__ den_final, const int* __restrict__ den_pdf,
    float* __restrict__ out, float* __restrict__ ws)
{
  cg::grid_group grid = cg::this_grid();
  float* QD = ws;                    // [2][B][SD]
  float* QN = QD + 2 * B_ * SD_;     // [2][B][SN]
  float* MD = QN + 2 * B_ * SN_;     // [2][B]
  float* MN = MD + 2 * B_;           // [2][B]
  float* LD = MN + 2 * B_;           // [B]
  float* LN = LD + B_;               // [B]

  __shared__ float WL[CPB * (SD_ + 4)];   // 8 x 1028 floats ~ 33 KB
  __shared__ float red[NTHR];

  const int tid = threadIdx.x;
  const int bid = blockIdx.x;
  const bool is_den = bid < NBD;
  const int colbase = (is_den ? bid : (bid - NBD)) * CPB;

  // Phase A: stage W slab (transposed, exp applied) into LDS — once.
  if (is_den) {
    for (int i = tid; i < CPB * SD_; i += NTHR) {
      const int s = i >> 3, c2 = i & 7;
      WL[c2 * (SD_ + 4) + s] = __expf(den_trans[(size_t)s * SD_ + colbase + c2]);
    }
  } else {
    for (int i = tid; i < CPB * SN_; i += NTHR) {
      const int s = i >> 3, c2 = i & 7;
      WL[c2 * (SN_ + 4) + s] = __expf(num_trans[(size_t)s * SN_ + colbase + c2]);
    }
  }
  __syncthreads();

  // Phase B: alpha0 = init + emis[:,0,:], max-normalized into buffer 1.
  if (bid < B_) {
    const int b = bid;
    float a0[4]; float lmax = -3.4e38f;
    for (int j = 0; j < 4; ++j) {
      const int s = tid + j * NTHR;
      const float a = den_init[s] + input[(size_t)b * T_ * P_ + den_pdf[s]];
      a0[j] = a; lmax = fmaxf(lmax, a);
    }
    red[tid] = lmax; __syncthreads();
    for (int off = 128; off; off >>= 1) { if (tid < off) red[tid] = fmaxf(red[tid], red[tid + off]); __syncthreads(); }
    const float m = red[0];
    for (int j = 0; j < 4; ++j) {
      const int s = tid + j * NTHR;
      QD[1 * B_ * SD_ + b * SD_ + s] = __expf(a0[j] - m);
    }
    if (tid == 0) { LD[b] = m; MD[1 * B_ + b] = 1.0f; }
    __syncthreads();
  } else if (bid < 2 * B_) {
    const int b = bid - B_;
    const float a = num_init[tid] + input[(size_t)b * T_ * P_ + num_pdf[tid]];
    red[tid] = a; __syncthreads();
    for (int off = 128; off; off >>= 1) { if (tid < off) red[tid] = fmaxf(red[tid], red[tid + off]); __syncthreads(); }
    const float m = red[0];
    QN[1 * B_ * SN_ + b * SN_ + tid] = __expf(a - m);
    if (tid == 0) { LN[b] = m; MN[1 * B_ + b] = 1.0f; }
    __syncthreads();
  }
  __threadfence();
  grid.sync();

  // Main recursion: 511 steps.
  if (is_den)
    run_path<SD_>(grid, input, seqlen, den_pdf, WL, red, QD, MD, LD, colbase, bid == 0);
  else
    run_path<SN_>(grid, input, seqlen, num_pdf, WL, red, QN, MN, LN, colbase, bid == NBD);

  // Epilogue: alpha_511 sits in buffer 0. Block 0 reduces both paths.
  if (bid == 0) {
    float sden = 0.f, snum = 0.f;
    for (int b2 = 0; b2 < B_; ++b2) {
      float p = 0.f;
      for (int s = tid; s < SD_; s += NTHR) p += QD[b2 * SD_ + s] * __expf(den_final[s]);
      red[tid] = p; __syncthreads();
      for (int off = 128; off; off >>= 1) { if (tid < off) red[tid] += red[tid + off]; __syncthreads(); }
      if (tid == 0) sden += LD[b2] + __logf(red[0]);
      __syncthreads();
      const float pn = QN[b2 * SN_ + tid] * __expf(num_final[tid]);
      red[tid] = pn; __syncthreads();
      for (int off = 128; off; off >>= 1) { if (tid < off) red[tid] += red[tid + off]; __syncthreads(); }
      if (tid == 0) snum += LN[b2] + __logf(red[0]);
      __syncthreads();
    }
    if (tid == 0) out[0] = -(snum - sden);
  }
}

extern "C" void kernel_launch(void* const* d_in, const int* in_sizes, int n_in,
                              void* d_out, int out_size, void* d_ws, size_t ws_size,
                              hipStream_t stream) {
  const float* input     = (const float*)d_in[0];
  const int*   seqlen    = (const int*)  d_in[1];
  const float* num_init  = (const float*)d_in[2];
  const float* num_trans = (const float*)d_in[3];
  const float* num_final = (const float*)d_in[4];
  const int*   num_pdf   = (const int*)  d_in[5];
  const float* den_init  = (const float*)d_in[6];
  const float* den_trans = (const float*)d_in[7];
  const float* den_final = (const float*)d_in[8];
  const int*   den_pdf   = (const int*)  d_in[9];
  float* out = (float*)d_out;
  float* ws  = (float*)d_ws;   // ~165 KB: Q double-buffers + M + L

  void* args[] = { &input, &seqlen, &num_init, &num_trans, &num_final, &num_pdf,
                   &den_init, &den_trans, &den_final, &den_pdf, &out, &ws };
  hipLaunchCooperativeKernel((void*)lfmmi_kernel, dim3(NBLK), dim3(NTHR),
                             args, 0, stream);
}

// Round 3
// 5753.668 us; speedup vs baseline: 3.8830x; 3.3542x over previous
//
#include <hip/hip_runtime.h>
#include <hip/hip_cooperative_groups.h>

#define B_ 16
#define T_ 512
#define P_ 2048
#define SN_ 256
#define SD_ 1024
#define CPB 16                // columns per block
#define NBD (SD_ / CPB)       // 64 den blocks
#define NBN (SN_ / CPB)       // 16 num blocks
#define NBLK (NBD + NBN)      // 80
#define NTHR 1024             // 16 c x 16 b x 4 kq
#define MAGIC 0x5A17C0DEu

// Agent-scope relaxed atomics: write-through / L2-bypass to the coherent
// point. No cache flush fences anywhere — this is the whole point.
#define ALF(p)    __hip_atomic_load((p),  __ATOMIC_RELAXED, __HIP_MEMORY_SCOPE_AGENT)
#define ASF(p, v) __hip_atomic_store((p), (v), __ATOMIC_RELAXED, __HIP_MEMORY_SCOPE_AGENT)

// Fence-free epoch barrier. __syncthreads drains vmcnt (compiler emits
// s_waitcnt vmcnt(0) before s_barrier), so this block's agent-scope q/M/L
// stores are at the coherent point before the arrival add is issued.
__device__ __forceinline__ void gbar(unsigned* __restrict__ C, int e) {
  __syncthreads();
  if (threadIdx.x == 0) {
    __hip_atomic_fetch_add(&C[e], 1u, __ATOMIC_RELAXED, __HIP_MEMORY_SCOPE_AGENT);
    while (__hip_atomic_load(&C[e], __ATOMIC_RELAXED, __HIP_MEMORY_SCOPE_AGENT) < NBLK)
      __builtin_amdgcn_s_sleep(1);
  }
  __syncthreads();
}

// Exp-space forward recursion. W slab (16 cols, transposed) LDS-resident.
// q_{t-1} staged global->LDS each step via coherent loads. M = lead block's
// own-16-column max (any sane scale works), L in lead registers.
template<int S>
__device__ __forceinline__ void run_path(
    const float* __restrict__ input, const int* __restrict__ seqlen,
    const int* __restrict__ pdf,
    float* __restrict__ qs, float* __restrict__ wsl, float* __restrict__ red,
    float* __restrict__ Q, float* __restrict__ M, float* __restrict__ L,
    unsigned* __restrict__ C, int colbase, bool lead)
{
  constexpr int SW = S + 4;       // padded LDS row stride
  constexpr int KS = S / 4;       // K slice per kq
  const int tid = threadIdx.x;
  const int c   = tid & 15;
  const int b   = (tid >> 4) & 15;
  const int kq  = tid >> 8;
  const int cglob = colbase + c;
  const int slen  = seqlen[b];
  const size_t inbase = (size_t)b * T_ * P_;
  const int mypdf = (kq == 0) ? pdf[cglob] : 0;
  const bool mwriter = lead && (kq == 0) && (c == 0);
  float Lreg = 0.f;

  for (int t = 1; t < T_; ++t) {
    const int pr = t & 1, pw = pr ^ 1;

    // Stage q_{t-1}[16][S] into LDS (coherent scalar loads, coalesced).
    const float* __restrict__ Qr = Q + pr * B_ * S;
    #pragma unroll
    for (int i = tid; i < B_ * S; i += NTHR) {
      const int bb = (S == 1024) ? (i >> 10) : (i >> 8);
      const int ss = i & (S - 1);
      qs[bb * SW + ss] = ALF(Qr + i);
    }
    __syncthreads();

    const bool live = (t < slen);
    float e_t = 0.f, carry = 0.f;
    if (kq == 0) {
      if (live) e_t = input[inbase + (size_t)t * P_ + mypdf];  // plain load: input immutable, L2 never invalidated
      else      carry = qs[b * SW + cglob];
    }

    const float* __restrict__ qrow = qs  + b * SW + kq * KS;
    const float* __restrict__ wrow = wsl + c * SW + kq * KS;
    float a0 = 0.f, a1 = 0.f, a2 = 0.f, a3 = 0.f;
    #pragma unroll 8
    for (int s = 0; s < KS; s += 4) {
      float4 qv = *(const float4*)(qrow + s);
      float4 wv = *(const float4*)(wrow + s);
      a0 = fmaf(qv.x, wv.x, a0);
      a1 = fmaf(qv.y, wv.y, a1);
      a2 = fmaf(qv.z, wv.z, a2);
      a3 = fmaf(qv.w, wv.w, a3);
    }
    red[tid] = (a0 + a1) + (a2 + a3);
    __syncthreads();

    if (kq == 0) {
      const float acc = red[tid] + red[tid + 256] + red[tid + 512] + red[tid + 768];
      const float Mv = ALF(M + (t & 1) * B_ + b);
      const float val = live ? (acc / Mv) * __expf(e_t) : carry;
      ASF(Q + pw * B_ * S + b * S + cglob, val);
      if (lead) {
        float mx = val;
        mx = fmaxf(mx, __shfl_xor(mx, 1));
        mx = fmaxf(mx, __shfl_xor(mx, 2));
        mx = fmaxf(mx, __shfl_xor(mx, 4));
        mx = fmaxf(mx, __shfl_xor(mx, 8));
        if (c == 0) {
          ASF(M + ((t & 1) ^ 1) * B_ + b, mx);     // scale for step t+1
          if (live) Lreg += __logf(Mv);            // log of scale used THIS step
          ASF(L + b, Lreg);
        }
      }
    }
    gbar(C, t);
  }
}

__global__ __launch_bounds__(NTHR) void lfmmi_kernel(
    const float* __restrict__ input, const int* __restrict__ seqlen,
    const float* __restrict__ num_init, const float* __restrict__ num_trans,
    const float* __restrict__ num_final, const int* __restrict__ num_pdf,
    const float* __restrict__ den_init, const float* __restrict__ den_trans,
    const float* __restrict__ den_final, const int* __restrict__ den_pdf,
    float* __restrict__ out, float* __restrict__ ws)
{
  float* QD = ws;                         // [2][16][1024]
  float* QN = QD + 2 * B_ * SD_;          // [2][16][256]
  float* MD = QN + 2 * B_ * SN_;          // [2][16]
  float* MN = MD + 2 * B_;                // [2][16]
  float* LD = MN + 2 * B_;                // [16]
  float* LN = LD + B_;                    // [16]
  unsigned* FL = (unsigned*)(LN + B_);    // init-done flag
  unsigned* C  = FL + 16;                 // [512] epoch counters

  __shared__ float qs [B_  * (SD_ + 4)];  // 64.3 KB
  __shared__ float wsl[CPB * (SD_ + 4)];  // 64.3 KB
  __shared__ float red[NTHR];             // 4 KB

  const int tid = threadIdx.x;
  const int bid = blockIdx.x;
  const bool is_den = bid < NBD;
  const int colbase = (is_den ? bid : (bid - NBD)) * CPB;
  const int c  = tid & 15;
  const int b  = (tid >> 4) & 15;
  const int kq = tid >> 8;

  // Block 0: zero the barrier counters (ws is poisoned 0xAA each launch),
  // then publish MAGIC. Other blocks spin on MAGIC before first barrier use.
  if (bid == 0) {
    for (int i = tid; i < 512; i += NTHR)
      __hip_atomic_store(&C[i], 0u, __ATOMIC_RELAXED, __HIP_MEMORY_SCOPE_AGENT);
    __syncthreads();
    if (tid == 0)
      __hip_atomic_store(FL, MAGIC, __ATOMIC_RELEASE, __HIP_MEMORY_SCOPE_AGENT);
  }

  // Stage W slab (transposed, exp applied) into LDS — once.
  if (is_den) {
    for (int i = tid; i < CPB * SD_; i += NTHR) {
      const int s = i >> 4, c2 = i & 15;
      wsl[c2 * (SD_ + 4) + s] = __expf(den_trans[(size_t)s * SD_ + colbase + c2]);
    }
  } else {
    for (int i = tid; i < CPB * SN_; i += NTHR) {
      const int s = i >> 4, c2 = i & 15;
      wsl[c2 * (SN_ + 4) + s] = __expf(num_trans[(size_t)s * SN_ + colbase + c2]);
    }
  }

  // q0 = exp(init + emis[:,0,:]) — no normalization needed (values ~e^±8),
  // first M correction kicks in at step 2. L starts at 0.
  if (kq == 0) {
    const int cg = colbase + c;
    const size_t inb = (size_t)b * T_ * P_;
    if (is_den) {
      const float v = __expf(den_init[cg] + input[inb + den_pdf[cg]]);
      ASF(QD + 1 * B_ * SD_ + b * SD_ + cg, v);
    } else {
      const float v = __expf(num_init[cg] + input[inb + num_pdf[cg]]);
      ASF(QN + 1 * B_ * SN_ + b * SN_ + cg, v);
    }
    // Leads init M slot for step 1 and L.
    if (c == 0) {
      if (bid == 0)   { ASF(MD + B_ + b, 1.0f); ASF(LD + b, 0.0f); }
      if (bid == NBD) { ASF(MN + B_ + b, 1.0f); ASF(LN + b, 0.0f); }
    }
  }

  // Wait for barrier-counter init, then epoch-0 barrier (publishes q0/M/W).
  if (tid == 0) {
    while (__hip_atomic_load(FL, __ATOMIC_ACQUIRE, __HIP_MEMORY_SCOPE_AGENT) != MAGIC)
      __builtin_amdgcn_s_sleep(1);
  }
  gbar(C, 0);

  // 511 recursion steps.
  if (is_den)
    run_path<SD_>(input, seqlen, den_pdf, qs, wsl, red, QD, MD, LD, C, colbase, bid == 0);
  else
    run_path<SN_>(input, seqlen, num_pdf, qs, wsl, red, QN, MN, LN, C, colbase, bid == NBD);

  // Epilogue: final q in buffer 0; block 0 reduces both paths.
  if (bid == 0) {
    float sden = 0.f, snum = 0.f;
    for (int b2 = 0; b2 < B_; ++b2) {
      float p = ALF(QD + b2 * SD_ + tid) * __expf(den_final[tid]);
      red[tid] = p; __syncthreads();
      for (int off = 512; off; off >>= 1) { if (tid < off) red[tid] += red[tid + off]; __syncthreads(); }
      if (tid == 0) sden += ALF(LD + b2) + __logf(red[0]);
      __syncthreads();
      float pn = (tid < SN_) ? ALF(QN + b2 * SN_ + tid) * __expf(num_final[tid]) : 0.f;
      red[tid] = pn; __syncthreads();
      for (int off = 512; off; off >>= 1) { if (tid < off) red[tid] += red[tid + off]; __syncthreads(); }
      if (tid == 0) snum += ALF(LN + b2) + __logf(red[0]);
      __syncthreads();
    }
    if (tid == 0) out[0] = -(snum - sden);
  }
}

extern "C" void kernel_launch(void* const* d_in, const int* in_sizes, int n_in,
                              void* d_out, int out_size, void* d_ws, size_t ws_size,
                              hipStream_t stream) {
  const float* input     = (const float*)d_in[0];
  const int*   seqlen    = (const int*)  d_in[1];
  const float* num_init  = (const float*)d_in[2];
  const float* num_trans = (const float*)d_in[3];
  const float* num_final = (const float*)d_in[4];
  const int*   num_pdf   = (const int*)  d_in[5];
  const float* den_init  = (const float*)d_in[6];
  const float* den_trans = (const float*)d_in[7];
  const float* den_final = (const float*)d_in[8];
  const int*   den_pdf   = (const int*)  d_in[9];
  float* out = (float*)d_out;
  float* ws  = (float*)d_ws;   // ~170 KB used

  void* args[] = { &input, &seqlen, &num_init, &num_trans, &num_final, &num_pdf,
                   &den_init, &den_trans, &den_final, &den_pdf, &out, &ws };
  hipLaunchCooperativeKernel((void*)lfmmi_kernel, dim3(NBLK), dim3(NTHR),
                             args, 0, stream);
}

// Round 4
// 2555.011 us; speedup vs baseline: 8.7443x; 2.2519x over previous
//
#include <hip/hip_runtime.h>

#define AG __HIP_MEMORY_SCOPE_AGENT
#define B_ 16
#define T_ 512
#define P_ 2048
#define SN_ 256
#define SD_ 1024
#define NGD 8                 // den groups (one b-pair each)
#define GB 16                 // blocks per den group (64 cols each)
#define NBD (NGD * GB)        // 128 den blocks
#define NBLK (NBD + B_)       // + 16 num blocks = 144
#define NTHR 1024
#define CHS 160               // chunk stride in floats (128 data + 2 M + pad)
#define SWD 513               // den W row stride (dwords), 513%32==1 -> conflict-light
#define SWN 129               // num W row stride (dwords)

__device__ __forceinline__ float    alf(const float* p){ return __hip_atomic_load(p, __ATOMIC_RELAXED, AG); }
__device__ __forceinline__ void     asf(float* p, float v){ __hip_atomic_store(p, v, __ATOMIC_RELAXED, AG); }
__device__ __forceinline__ void     rsu(unsigned* p, unsigned v){ __hip_atomic_store(p, v, __ATOMIC_RELEASE, AG); }
__device__ __forceinline__ void wait_eq(unsigned* p, unsigned v){
  while (__hip_atomic_load(p, __ATOMIC_RELAXED, AG) != v) __builtin_amdgcn_s_sleep(2);
  asm volatile("" ::: "memory");   // keep data loads after the flag match
}
// f32 -> bf16 with round-to-nearest-even (init-time only)
__device__ __forceinline__ unsigned bf16rne(float x){
  unsigned u = __float_as_uint(x);
  return (u + 0x7FFFu + ((u >> 16) & 1u)) >> 16;
}
__device__ __forceinline__ float blo(unsigned p){ return __uint_as_float(p << 16); }
__device__ __forceinline__ float bhi(unsigned p){ return __uint_as_float(p & 0xFFFF0000u); }

// Exp-space forward recursion, dataflow (no grid barrier):
//   q_t[b,c] = (sum_k q_{t-1}[b,k] * W[k,c]) / M_t[b] * exp(e_t[b,c])
// den: 8 groups x 16 blocks; group owns b-pair {2g,2g+1}; block owns 64 cols.
// Exchange: 512B chunk + epoch flag (exact-match vs 0xAA poison), 2 parities.
// num: W fits LDS (bf16) -> 16 fully independent blocks, zero sync.
__global__ __launch_bounds__(NTHR) void lfmmi_kernel(
    const float* __restrict__ input, const int* __restrict__ seqlen,
    const float* __restrict__ num_init, const float* __restrict__ num_trans,
    const float* __restrict__ num_final, const int* __restrict__ num_pdf,
    const float* __restrict__ den_init, const float* __restrict__ den_trans,
    const float* __restrict__ den_final, const int* __restrict__ den_pdf,
    float* __restrict__ out, float* __restrict__ ws)
{
  __shared__ __align__(16) unsigned char smem[147968];
  const int tid = threadIdx.x;
  const int bid = blockIdx.x;

  // workspace carve
  float*    Qc     = ws;                               // [2][NGD][GB][CHS]
  unsigned* F      = (unsigned*)(Qc + 2*NGD*GB*CHS);   // [2][NGD][GB][16]
  float*    DenRes = (float*)(F + 2*NGD*GB*16);        // [16]
  float*    NumRes = DenRes + 16;                      // [16]
  unsigned* DF     = (unsigned*)(NumRes + 16);         // [NGD][16]
  unsigned* NF     = DF + NGD*16;                      // [16][16]

  if (bid < NBD) {
    // ================= DEN =================
    const int g = bid >> 4, r = bid & 15;
    unsigned* WL  = (unsigned*)smem;                   // [64][513] dwords (bf16 pairs)
    float*    qs  = (float*)(smem + 131328);           // [2][1024]
    float*    red = (float*)(smem + 139520);           // [16][128] (2048 floats)
    float*    Ms  = (float*)(smem + 147712);           // [2]
    const int col0 = r * 64;

    // --- stage W slab: WL[c][k] = bf16(exp(trans[k][col0+c])), coalesced ---
    {
      const int c = tid & 63, jj = tid >> 6;
      for (int j0 = 0; j0 < 512; j0 += 16) {
        const int j = j0 + jj, k = 2 * j;
        const float w0 = __expf(den_trans[(size_t)k * SD_ + col0 + c]);
        const float w1 = __expf(den_trans[(size_t)(k + 1) * SD_ + col0 + c]);
        WL[c * SWD + j] = bf16rne(w0) | (bf16rne(w1) << 16);
      }
    }

    const int cg = tid & 31, kq = tid >> 5;   // compute tile: cols {cg, cg+32}, k-slice 32
    const int wv = tid >> 6, ln = tid & 63;   // staging: wave wv handles chunk wv

    int pdfc = 0, slen_o = 0, cglob_o = 0;
    size_t inb_o = 0;
    if (tid < 128) {               // owner o=tid: c=o&63, b2=o>>6
      cglob_o = col0 + (tid & 63);
      const int b_o = 2 * g + (tid >> 6);
      pdfc   = den_pdf[cglob_o];
      slen_o = seqlen[b_o];
      inb_o  = (size_t)b_o * T_ * P_;
    }

    // --- init publish (t=0, parity 0) ---
    float* chunk0 = Qc + ((size_t)(0 * NGD + g) * GB + r) * CHS;
    if (tid < 128) {
      const float v = __expf(den_init[cglob_o] + input[inb_o + pdfc]);
      asf(chunk0 + tid, v);
      if (r == 0) {
        float mx = v;
        #pragma unroll
        for (int d = 1; d < 64; d <<= 1) mx = fmaxf(mx, __shfl_xor(mx, d));
        if (ln == 0) asf(chunk0 + 128 + (tid >> 6), mx);
      }
    }
    __syncthreads();                                     // drain stores (per-wave vmcnt)
    if (tid == 0) rsu(F + ((0 * NGD + g) * GB + r) * 16, 0u);

    float Lreg = 0.f;
    for (int t = 1; t <= 511; ++t) {
      const int pp = (t - 1) & 1, pc = t & 1;
      // owner: prefetch emission gather (plain load, input immutable/cached)
      float ein = 0.f; bool live_o = false;
      if (tid < 128) {
        live_o = (t < slen_o);
        if (live_o) ein = input[inb_o + (size_t)t * P_ + pdfc];
      }
      // stage q_{t-1}: wave wv polls producer wv's flag, loads 512B chunk
      wait_eq(F + ((pp * NGD + g) * GB + wv) * 16, (unsigned)(t - 1));
      {
        float* ch = Qc + ((size_t)(pp * NGD + g) * GB + wv) * CHS;
        qs[wv * 64 + ln]        = alf(ch + ln);
        qs[1024 + wv * 64 + ln] = alf(ch + 64 + ln);
        if (wv == 0 && ln < 2) Ms[ln] = alf(ch + 128 + ln);
      }
      __syncthreads();
      // compute 2c x 2b register tile over k-slice of 32
      float a00 = 0.f, a01 = 0.f, a10 = 0.f, a11 = 0.f;
      {
        const unsigned* wA = WL + cg * SWD + kq * 16;
        const unsigned* wB = wA + 32 * SWD;
        const float* q0 = qs + kq * 32;
        const float* q1 = qs + 1024 + kq * 32;
        #pragma unroll
        for (int j = 0; j < 16; ++j) {
          const unsigned pa = wA[j], pb = wB[j];
          const float2 f0 = *(const float2*)(q0 + 2 * j);
          const float2 f1 = *(const float2*)(q1 + 2 * j);
          a00 = fmaf(f0.x, blo(pa), a00); a00 = fmaf(f0.y, bhi(pa), a00);
          a01 = fmaf(f0.x, blo(pb), a01); a01 = fmaf(f0.y, bhi(pb), a01);
          a10 = fmaf(f1.x, blo(pa), a10); a10 = fmaf(f1.y, bhi(pa), a10);
          a11 = fmaf(f1.x, blo(pb), a11); a11 = fmaf(f1.y, bhi(pb), a11);
        }
      }
      // fold the kq-pair within the wave (lanes 32 apart), park in red
      a00 += __shfl_xor(a00, 32); a01 += __shfl_xor(a01, 32);
      a10 += __shfl_xor(a10, 32); a11 += __shfl_xor(a11, 32);
      if (ln < 32) {
        float* rw = red + wv * 128;
        rw[cg] = a00; rw[32 + cg] = a01; rw[64 + cg] = a10; rw[96 + cg] = a11;
      }
      __syncthreads();
      // owners: 16-way fold, scale, publish
      float* myChunk = Qc + ((size_t)(pc * NGD + g) * GB + r) * CHS;
      if (tid < 128) {
        float acc = 0.f;
        #pragma unroll
        for (int w = 0; w < 16; ++w) acc += red[w * 128 + tid];
        const float Mv = Ms[tid >> 6];
        const float val = live_o ? (acc / Mv) * __expf(ein)
                                 : qs[(tid >> 6) * 1024 + cglob_o];   // frozen carry
        asf(myChunk + tid, val);
        if (r == 0) {
          float mx = val;
          #pragma unroll
          for (int d = 1; d < 64; d <<= 1) mx = fmaxf(mx, __shfl_xor(mx, d));
          if (ln == 0) asf(myChunk + 128 + (tid >> 6), mx);
          if ((tid == 0 || tid == 64) && live_o) Lreg += __logf(Mv);
        }
      }
      __syncthreads();                                   // drain all waves' stores
      if (tid == 0) rsu(F + ((pc * NGD + g) * GB + r) * 16, (unsigned)t);
    }

    // --- epilogue: r0 reduces final q for its 2 b's; g0r0 combines all ---
    if (r == 0) {
      wait_eq(F + ((1 * NGD + g) * GB + wv) * 16, 511u);
      {
        float* ch = Qc + ((size_t)(1 * NGD + g) * GB + wv) * CHS;
        qs[wv * 64 + ln]        = alf(ch + ln);
        qs[1024 + wv * 64 + ln] = alf(ch + 64 + ln);
      }
      __syncthreads();
      const int b2e = tid >> 9, ce = tid & 511;
      red[tid] = qs[b2e * 1024 + ce] * __expf(den_final[ce])
               + qs[b2e * 1024 + 512 + ce] * __expf(den_final[512 + ce]);
      __syncthreads();
      for (int off = 256; off; off >>= 1) {
        const int base = (tid >= 512) ? 512 : 0, i = tid - base;
        if (i < off) red[base + i] += red[base + i + off];
        __syncthreads();
      }
      if (tid == 0)  asf(DenRes + 2 * g,     Lreg + __logf(red[0]));
      if (tid == 64) asf(DenRes + 2 * g + 1, Lreg + __logf(red[512]));
      __syncthreads();
      if (tid == 0) rsu(DF + g * 16, 0x600D0000u | (unsigned)g);
      if (g == 0 && tid == 0) {
        for (int g2 = 0; g2 < NGD; ++g2) wait_eq(DF + g2 * 16, 0x600D0000u | (unsigned)g2);
        for (int b2 = 0; b2 < B_; ++b2)  wait_eq(NF + b2 * 16, 0x600D0100u | (unsigned)b2);
        float sden = 0.f, snum = 0.f;
        for (int i = 0; i < 16; ++i) { sden += alf(DenRes + i); snum += alf(NumRes + i); }
        out[0] = -(snum - sden);
      }
    }
  } else {
    // ================= NUM (fully block-local) =================
    const int b = bid - NBD;
    unsigned* WLn  = (unsigned*)smem;                  // [256][129] dwords
    float*    qn   = (float*)(smem + 132096);          // [2][256]
    float*    redn = (float*)(smem + 134144);          // [1024]
    float*    Msn  = (float*)(smem + 138240);          // [8]
    const size_t inb = (size_t)b * T_ * P_;
    const int slen = seqlen[b];

    {
      const int c = tid & 255, jj = tid >> 8;
      for (int j0 = 0; j0 < 128; j0 += 4) {
        const int j = j0 + jj, k = 2 * j;
        const float w0 = __expf(num_trans[(size_t)k * SN_ + c]);
        const float w1 = __expf(num_trans[(size_t)(k + 1) * SN_ + c]);
        WLn[c * SWN + j] = bf16rne(w0) | (bf16rne(w1) << 16);
      }
    }
    int pdfc = 0;
    if (tid < 256) pdfc = num_pdf[tid];
    // init t=0 -> qn[0]
    if (tid < 256) {
      const float v = __expf(num_init[tid] + input[inb + pdfc]);
      qn[tid] = v;
      float mx = v;
      #pragma unroll
      for (int d = 1; d < 64; d <<= 1) mx = fmaxf(mx, __shfl_xor(mx, d));
      if ((tid & 63) == 0) Msn[1 + (tid >> 6)] = mx;
    }
    __syncthreads();
    if (tid == 0) Msn[0] = fmaxf(fmaxf(Msn[1], Msn[2]), fmaxf(Msn[3], Msn[4]));
    __syncthreads();

    float Lreg = 0.f;
    const int cN = tid & 255, kqN = tid >> 8;
    int tlast = 0;
    for (int t = 1; t <= 511; ++t) {
      if (t >= slen) break;        // frozen forever -> done (uniform branch)
      tlast = t;
      const int pr = (t - 1) & 1, pw = t & 1;
      float ein = 0.f;
      if (tid < 256) ein = input[inb + (size_t)t * P_ + pdfc];
      float acc = 0.f;
      {
        const unsigned* wp = WLn + cN * SWN + kqN * 32;
        const float* qp = qn + pr * 256 + kqN * 64;
        #pragma unroll
        for (int j = 0; j < 32; ++j) {
          const unsigned p = wp[j];
          const float2 f = *(const float2*)(qp + 2 * j);
          acc = fmaf(f.x, blo(p), acc);
          acc = fmaf(f.y, bhi(p), acc);
        }
      }
      redn[kqN * 256 + cN] = acc;
      __syncthreads();
      if (tid < 256) {
        const float s = redn[tid] + redn[256 + tid] + redn[512 + tid] + redn[768 + tid];
        const float Mv = Msn[0];
        const float val = (s / Mv) * __expf(ein);
        qn[pw * 256 + tid] = val;
        float mx = val;
        #pragma unroll
        for (int d = 1; d < 64; d <<= 1) mx = fmaxf(mx, __shfl_xor(mx, d));
        if ((tid & 63) == 0) Msn[1 + (tid >> 6)] = mx;
        if (tid == 0) Lreg += __logf(Mv);
      }
      __syncthreads();
      if (tid == 0) Msn[0] = fmaxf(fmaxf(Msn[1], Msn[2]), fmaxf(Msn[3], Msn[4]));
      __syncthreads();
    }
    const int cur = tlast & 1;
    if (tid < 256) redn[tid] = qn[cur * 256 + tid] * __expf(num_final[tid]);
    __syncthreads();
    for (int off = 128; off; off >>= 1) {
      if (tid < off) redn[tid] += redn[tid + off];
      __syncthreads();
    }
    if (tid == 0) {
      asf(NumRes + b, Lreg + __logf(redn[0]));
      rsu(NF + b * 16, 0x600D0100u | (unsigned)b);
    }
  }
}

extern "C" void kernel_launch(void* const* d_in, const int* in_sizes, int n_in,
                              void* d_out, int out_size, void* d_ws, size_t ws_size,
                              hipStream_t stream) {
  const float* input     = (const float*)d_in[0];
  const int*   seqlen    = (const int*)  d_in[1];
  const float* num_init  = (const float*)d_in[2];
  const float* num_trans = (const float*)d_in[3];
  const float* num_final = (const float*)d_in[4];
  const int*   num_pdf   = (const int*)  d_in[5];
  const float* den_init  = (const float*)d_in[6];
  const float* den_trans = (const float*)d_in[7];
  const float* den_final = (const float*)d_in[8];
  const int*   den_pdf   = (const int*)  d_in[9];
  float* out = (float*)d_out;
  float* ws  = (float*)d_ws;   // ~730 KB used (chunks + flags + results)

  void* args[] = { &input, &seqlen, &num_init, &num_trans, &num_final, &num_pdf,
                   &den_init, &den_trans, &den_final, &den_pdf, &out, &ws };
  hipLaunchCooperativeKernel((void*)lfmmi_kernel, dim3(NBLK), dim3(NTHR),
                             args, 0, stream);
}